// Round 1
// baseline (273.543 us; speedup 1.0000x reference)
//
#include <hip/hip_runtime.h>
#include <math.h>

#define FDIM 256
#define NH 8
#define HD 32
#define NQ 4096
#define NKEY 4096
#define CAP 512
#define R2 9.0f

// ---------------------------------------------------------------------------
// GEMM: C[M,N] = A[M,256] * W[N,256]^T + bias[N]   (all fp32, row-major)
// 64x64 tile, BK=16, 256 threads, 4x4 micro-tile per thread.
// LDS pad = +4 floats so every row stays 16B-aligned for ds_read_b128.
// ---------------------------------------------------------------------------
__global__ __launch_bounds__(256) void gemm_bt(const float* __restrict__ A,
                                               const float* __restrict__ W,
                                               const float* __restrict__ bias,
                                               float* __restrict__ C) {
    __shared__ float As[16][68];
    __shared__ float Ws[16][68];
    const int t  = threadIdx.x;
    const int m0 = blockIdx.y * 64;
    const int n0 = blockIdx.x * 64;
    const int lr = t >> 2;   // 0..63 staging row
    const int ls = t & 3;    // 0..3 staging 4-col segment
    const int tm = t >> 4;   // 0..15
    const int tn = t & 15;   // 0..15

    float acc[4][4];
#pragma unroll
    for (int i = 0; i < 4; ++i)
#pragma unroll
        for (int j = 0; j < 4; ++j) acc[i][j] = 0.f;

    for (int k0 = 0; k0 < 256; k0 += 16) {
        float4 av = *(const float4*)(A + (size_t)(m0 + lr) * 256 + k0 + ls * 4);
        float4 wv = *(const float4*)(W + (size_t)(n0 + lr) * 256 + k0 + ls * 4);
        __syncthreads();  // everyone done reading previous tile
        As[ls * 4 + 0][lr] = av.x; As[ls * 4 + 1][lr] = av.y;
        As[ls * 4 + 2][lr] = av.z; As[ls * 4 + 3][lr] = av.w;
        Ws[ls * 4 + 0][lr] = wv.x; Ws[ls * 4 + 1][lr] = wv.y;
        Ws[ls * 4 + 2][lr] = wv.z; Ws[ls * 4 + 3][lr] = wv.w;
        __syncthreads();
#pragma unroll
        for (int kk = 0; kk < 16; ++kk) {
            float4 a4 = *(const float4*)&As[kk][tm * 4];
            float4 b4 = *(const float4*)&Ws[kk][tn * 4];
            float ar[4] = {a4.x, a4.y, a4.z, a4.w};
            float br[4] = {b4.x, b4.y, b4.z, b4.w};
#pragma unroll
            for (int i = 0; i < 4; ++i)
#pragma unroll
                for (int j = 0; j < 4; ++j)
                    acc[i][j] = fmaf(ar[i], br[j], acc[i][j]);
        }
    }

    float4 bb = *(const float4*)(bias + n0 + tn * 4);
    float br[4] = {bb.x, bb.y, bb.z, bb.w};
#pragma unroll
    for (int i = 0; i < 4; ++i) {
        float4 o;
        o.x = acc[i][0] + br[0];
        o.y = acc[i][1] + br[1];
        o.z = acc[i][2] + br[2];
        o.w = acc[i][3] + br[3];
        *(float4*)(C + (size_t)(m0 + tm * 4 + i) * 256 + n0 + tn * 4) = o;
    }
}

// ---------------------------------------------------------------------------
// Neighbor list build: one wave per query. Ballot-compacted u16 indices.
// Distance arithmetic matches the reference op-for-op (no FMA contraction).
// ---------------------------------------------------------------------------
__global__ __launch_bounds__(256) void build_nbr(const float* __restrict__ qc,
                                                 const float* __restrict__ kc,
                                                 unsigned short* __restrict__ nbr,
                                                 int* __restrict__ cnt) {
    const int q    = blockIdx.x * 4 + (threadIdx.x >> 6);
    const int lane = threadIdx.x & 63;
    const float qx = qc[q * 3 + 0];
    const float qy = qc[q * 3 + 1];
    const float qz = qc[q * 3 + 2];
    int base = 0;
    for (int k0 = 0; k0 < NKEY; k0 += 64) {
        const int k = k0 + lane;
        float dx = __fsub_rn(qx, kc[k * 3 + 0]);
        float dy = __fsub_rn(qy, kc[k * 3 + 1]);
        float dz = __fsub_rn(qz, kc[k * 3 + 2]);
        float d2 = __fadd_rn(__fadd_rn(__fmul_rn(dx, dx), __fmul_rn(dy, dy)),
                             __fmul_rn(dz, dz));
        bool valid = (d2 <= R2);
        unsigned long long bal = __ballot(valid);
        if (valid) {
            int pos = base + __popcll(bal & ((1ull << lane) - 1ull));
            if (pos < CAP) nbr[(size_t)q * CAP + pos] = (unsigned short)k;
        }
        base += __popcll(bal);
    }
    if (lane == 0) cnt[q] = (base > CAP) ? CAP : base;
}

// ---------------------------------------------------------------------------
// Sparse attention: one wave per query, all 8 heads.
// lane = h*8 + s ; the 8 lanes of a head split that query's neighbor list.
// Per-lane online softmax, then 3-step xor-shuffle merge within the head group.
// ---------------------------------------------------------------------------
__global__ __launch_bounds__(256) void sparse_attn(const float* __restrict__ Q,
                                                   const float* __restrict__ K,
                                                   const float* __restrict__ V,
                                                   const unsigned short* __restrict__ nbr,
                                                   const int* __restrict__ cnt,
                                                   float* __restrict__ O) {
    const int q    = blockIdx.x * 4 + (threadIdx.x >> 6);
    const int lane = threadIdx.x & 63;
    const int h    = lane >> 3;  // head 0..7
    const int s    = lane & 7;   // sub-lane 0..7

    const float* qrow = Q + (size_t)q * FDIM + h * HD;
    float qv[32];
#pragma unroll
    for (int i = 0; i < 8; ++i) {
        float4 tq = *(const float4*)(qrow + i * 4);
        qv[i * 4 + 0] = tq.x; qv[i * 4 + 1] = tq.y;
        qv[i * 4 + 2] = tq.z; qv[i * 4 + 3] = tq.w;
    }

    float o[32];
#pragma unroll
    for (int i = 0; i < 32; ++i) o[i] = 0.f;
    float m = -INFINITY, l = 0.f;

    const int n = cnt[q];
    const unsigned short* nl = nbr + (size_t)q * CAP;

    for (int j = s; j < n; j += 8) {
        const int k = nl[j];
        const float* krow = K + (size_t)k * FDIM + h * HD;
        float p0 = 0.f, p1 = 0.f, p2 = 0.f, p3 = 0.f;
#pragma unroll
        for (int i = 0; i < 8; ++i) {
            float4 kv = *(const float4*)(krow + i * 4);
            p0 = fmaf(qv[i * 4 + 0], kv.x, p0);
            p1 = fmaf(qv[i * 4 + 1], kv.y, p1);
            p2 = fmaf(qv[i * 4 + 2], kv.z, p2);
            p3 = fmaf(qv[i * 4 + 3], kv.w, p3);
        }
        const float sc = ((p0 + p1) + (p2 + p3)) * 0.17677669529663687f;
        const float newm  = fmaxf(m, sc);
        const float scale = __expf(m - newm);   // first iter: exp(-inf)=0
        const float p     = __expf(sc - newm);
        l = l * scale + p;
        const float* vrow = V + (size_t)k * FDIM + h * HD;
#pragma unroll
        for (int i = 0; i < 8; ++i) {
            float4 vv = *(const float4*)(vrow + i * 4);
            o[i * 4 + 0] = o[i * 4 + 0] * scale + p * vv.x;
            o[i * 4 + 1] = o[i * 4 + 1] * scale + p * vv.y;
            o[i * 4 + 2] = o[i * 4 + 2] * scale + p * vv.z;
            o[i * 4 + 3] = o[i * 4 + 3] * scale + p * vv.w;
        }
        m = newm;
    }

    // merge the 8 sub-lanes of this head
    float gm = m;
#pragma unroll
    for (int d = 1; d < 8; d <<= 1)
        gm = fmaxf(gm, __shfl_xor(gm, d, 64));
    const float sc2 = __expf(m - gm);  // lanes with no work: exp(-inf)=0
    l *= sc2;
#pragma unroll
    for (int i = 0; i < 32; ++i) o[i] *= sc2;
#pragma unroll
    for (int d = 1; d < 8; d <<= 1) {
        l += __shfl_xor(l, d, 64);
#pragma unroll
        for (int i = 0; i < 32; ++i) o[i] += __shfl_xor(o[i], d, 64);
    }

    if (s == 0) {
        const float inv = 1.0f / l;
        float* orow = O + (size_t)q * FDIM + h * HD;
#pragma unroll
        for (int i = 0; i < 8; ++i) {
            float4 t;
            t.x = o[i * 4 + 0] * inv; t.y = o[i * 4 + 1] * inv;
            t.z = o[i * 4 + 2] * inv; t.w = o[i * 4 + 3] * inv;
            *(float4*)(orow + i * 4) = t;
        }
    }
}

// ---------------------------------------------------------------------------
extern "C" void kernel_launch(void* const* d_in, const int* in_sizes, int n_in,
                              void* d_out, int out_size, void* d_ws, size_t ws_size,
                              hipStream_t stream) {
    const float* cur_feats  = (const float*)d_in[0];
    const float* hist_feats = (const float*)d_in[1];
    const float* cur_coords = (const float*)d_in[2];
    const float* hist_coords= (const float*)d_in[3];
    const float* Wq = (const float*)d_in[4];
    const float* bq = (const float*)d_in[5];
    const float* Wk = (const float*)d_in[6];
    const float* bk = (const float*)d_in[7];
    const float* Wv = (const float*)d_in[8];
    const float* bv = (const float*)d_in[9];
    const float* Wo = (const float*)d_in[10];
    const float* bo = (const float*)d_in[11];
    float* out = (float*)d_out;

    char* w = (char*)d_ws;
    const size_t MB4 = (size_t)NQ * FDIM * sizeof(float);  // 4 MiB
    float*          Qb  = (float*)(w);
    float*          Kb  = (float*)(w + MB4);
    float*          Vb  = (float*)(w + 2 * MB4);
    float*          Ob  = (float*)(w + 3 * MB4);
    unsigned short* nbr = (unsigned short*)(w + 4 * MB4);
    int*            cnt = (int*)(w + 4 * MB4 + (size_t)NQ * CAP * sizeof(unsigned short));

    dim3 ggrid(FDIM / 64, NQ / 64, 1);

    gemm_bt<<<ggrid, 256, 0, stream>>>(cur_feats,  Wq, bq, Qb);
    gemm_bt<<<ggrid, 256, 0, stream>>>(hist_feats, Wk, bk, Kb);
    gemm_bt<<<ggrid, 256, 0, stream>>>(hist_feats, Wv, bv, Vb);

    build_nbr<<<NQ / 4, 256, 0, stream>>>(cur_coords, hist_coords, nbr, cnt);

    sparse_attn<<<NQ / 4, 256, 0, stream>>>(Qb, Kb, Vb, nbr, cnt, Ob);

    gemm_bt<<<ggrid, 256, 0, stream>>>(Ob, Wo, bo, out);
}

// Round 2
// 177.365 us; speedup vs baseline: 1.5423x; 1.5423x over previous
//
#include <hip/hip_runtime.h>
#include <hip/hip_bf16.h>
#include <math.h>

#define FDIM 256
#define NH 8
#define HD 32
#define NQ 4096
#define NKEY 4096
#define CAP 512
#define R2 9.0f

typedef unsigned short ushort_t;
typedef ushort_t u8vec __attribute__((ext_vector_type(8)));
typedef ushort_t u4vec __attribute__((ext_vector_type(4)));

__device__ __forceinline__ float bf2f(ushort_t u) {
    union { unsigned int i; float f; } c;
    c.i = ((unsigned int)u) << 16;
    return c.f;
}
__device__ __forceinline__ ushort_t f2bf(float f) {
    __hip_bfloat16 b = __float2bfloat16(f);  // round-to-nearest-even
    return *reinterpret_cast<ushort_t*>(&b);
}

// ---------------------------------------------------------------------------
// Fused Q/K/V projection. blockIdx.z: 0 = Q (fp32 out), 1 = K, 2 = V
// (bf16 out into interleaved KV rows: KV[k][0:256]=K, KV[k][256:512]=V).
// 64x64 tile, BK=16, 256 threads, 4x4 micro-tile. 768 blocks -> 3 blocks/CU.
// ---------------------------------------------------------------------------
__global__ __launch_bounds__(256) void qkv_gemm(const float* __restrict__ cur,
                                                const float* __restrict__ hist,
                                                const float* __restrict__ Wq,
                                                const float* __restrict__ bq,
                                                const float* __restrict__ Wk,
                                                const float* __restrict__ bk,
                                                const float* __restrict__ Wv,
                                                const float* __restrict__ bv,
                                                float* __restrict__ Qout,
                                                ushort_t* __restrict__ KV) {
    __shared__ float As[16][68];
    __shared__ float Ws[16][68];
    const int z = blockIdx.z;
    const float* A    = (z == 0) ? cur : hist;
    const float* W    = (z == 0) ? Wq : (z == 1) ? Wk : Wv;
    const float* bias = (z == 0) ? bq : (z == 1) ? bk : bv;

    const int t  = threadIdx.x;
    const int m0 = blockIdx.y * 64;
    const int n0 = blockIdx.x * 64;
    const int lr = t >> 2;
    const int ls = t & 3;
    const int tm = t >> 4;
    const int tn = t & 15;

    float acc[4][4];
#pragma unroll
    for (int i = 0; i < 4; ++i)
#pragma unroll
        for (int j = 0; j < 4; ++j) acc[i][j] = 0.f;

    for (int k0 = 0; k0 < 256; k0 += 16) {
        float4 av = *(const float4*)(A + (size_t)(m0 + lr) * 256 + k0 + ls * 4);
        float4 wv = *(const float4*)(W + (size_t)(n0 + lr) * 256 + k0 + ls * 4);
        __syncthreads();
        As[ls * 4 + 0][lr] = av.x; As[ls * 4 + 1][lr] = av.y;
        As[ls * 4 + 2][lr] = av.z; As[ls * 4 + 3][lr] = av.w;
        Ws[ls * 4 + 0][lr] = wv.x; Ws[ls * 4 + 1][lr] = wv.y;
        Ws[ls * 4 + 2][lr] = wv.z; Ws[ls * 4 + 3][lr] = wv.w;
        __syncthreads();
#pragma unroll
        for (int kk = 0; kk < 16; ++kk) {
            float4 a4 = *(const float4*)&As[kk][tm * 4];
            float4 b4 = *(const float4*)&Ws[kk][tn * 4];
            float ar[4] = {a4.x, a4.y, a4.z, a4.w};
            float br[4] = {b4.x, b4.y, b4.z, b4.w};
#pragma unroll
            for (int i = 0; i < 4; ++i)
#pragma unroll
                for (int j = 0; j < 4; ++j)
                    acc[i][j] = fmaf(ar[i], br[j], acc[i][j]);
        }
    }

    float4 bb = *(const float4*)(bias + n0 + tn * 4);
    float br[4] = {bb.x, bb.y, bb.z, bb.w};
    if (z == 0) {
#pragma unroll
        for (int i = 0; i < 4; ++i) {
            float4 o;
            o.x = acc[i][0] + br[0];
            o.y = acc[i][1] + br[1];
            o.z = acc[i][2] + br[2];
            o.w = acc[i][3] + br[3];
            *(float4*)(Qout + (size_t)(m0 + tm * 4 + i) * 256 + n0 + tn * 4) = o;
        }
    } else {
        const int off = (z == 1) ? 0 : 256;
#pragma unroll
        for (int i = 0; i < 4; ++i) {
            u4vec u;
#pragma unroll
            for (int j = 0; j < 4; ++j) u[j] = f2bf(acc[i][j] + br[j]);
            *(u4vec*)(KV + (size_t)(m0 + tm * 4 + i) * 512 + off + n0 + tn * 4) = u;
        }
    }
}

// ---------------------------------------------------------------------------
// O-projection GEMM (fp32): C = A * Wo^T + bo
// ---------------------------------------------------------------------------
__global__ __launch_bounds__(256) void gemm_bt(const float* __restrict__ A,
                                               const float* __restrict__ W,
                                               const float* __restrict__ bias,
                                               float* __restrict__ C) {
    __shared__ float As[16][68];
    __shared__ float Ws[16][68];
    const int t  = threadIdx.x;
    const int m0 = blockIdx.y * 64;
    const int n0 = blockIdx.x * 64;
    const int lr = t >> 2;
    const int ls = t & 3;
    const int tm = t >> 4;
    const int tn = t & 15;

    float acc[4][4];
#pragma unroll
    for (int i = 0; i < 4; ++i)
#pragma unroll
        for (int j = 0; j < 4; ++j) acc[i][j] = 0.f;

    for (int k0 = 0; k0 < 256; k0 += 16) {
        float4 av = *(const float4*)(A + (size_t)(m0 + lr) * 256 + k0 + ls * 4);
        float4 wv = *(const float4*)(W + (size_t)(n0 + lr) * 256 + k0 + ls * 4);
        __syncthreads();
        As[ls * 4 + 0][lr] = av.x; As[ls * 4 + 1][lr] = av.y;
        As[ls * 4 + 2][lr] = av.z; As[ls * 4 + 3][lr] = av.w;
        Ws[ls * 4 + 0][lr] = wv.x; Ws[ls * 4 + 1][lr] = wv.y;
        Ws[ls * 4 + 2][lr] = wv.z; Ws[ls * 4 + 3][lr] = wv.w;
        __syncthreads();
#pragma unroll
        for (int kk = 0; kk < 16; ++kk) {
            float4 a4 = *(const float4*)&As[kk][tm * 4];
            float4 b4 = *(const float4*)&Ws[kk][tn * 4];
            float ar[4] = {a4.x, a4.y, a4.z, a4.w};
            float br[4] = {b4.x, b4.y, b4.z, b4.w};
#pragma unroll
            for (int i = 0; i < 4; ++i)
#pragma unroll
                for (int j = 0; j < 4; ++j)
                    acc[i][j] = fmaf(ar[i], br[j], acc[i][j]);
        }
    }

    float4 bb = *(const float4*)(bias + n0 + tn * 4);
    float br[4] = {bb.x, bb.y, bb.z, bb.w};
#pragma unroll
    for (int i = 0; i < 4; ++i) {
        float4 o;
        o.x = acc[i][0] + br[0];
        o.y = acc[i][1] + br[1];
        o.z = acc[i][2] + br[2];
        o.w = acc[i][3] + br[3];
        *(float4*)(C + (size_t)(m0 + tm * 4 + i) * 256 + n0 + tn * 4) = o;
    }
}

// ---------------------------------------------------------------------------
// Neighbor list build (unchanged): exact reference arithmetic order.
// ---------------------------------------------------------------------------
__global__ __launch_bounds__(256) void build_nbr(const float* __restrict__ qc,
                                                 const float* __restrict__ kc,
                                                 unsigned short* __restrict__ nbr,
                                                 int* __restrict__ cnt) {
    const int q    = blockIdx.x * 4 + (threadIdx.x >> 6);
    const int lane = threadIdx.x & 63;
    const float qx = qc[q * 3 + 0];
    const float qy = qc[q * 3 + 1];
    const float qz = qc[q * 3 + 2];
    int base = 0;
    for (int k0 = 0; k0 < NKEY; k0 += 64) {
        const int k = k0 + lane;
        float dx = __fsub_rn(qx, kc[k * 3 + 0]);
        float dy = __fsub_rn(qy, kc[k * 3 + 1]);
        float dz = __fsub_rn(qz, kc[k * 3 + 2]);
        float d2 = __fadd_rn(__fadd_rn(__fmul_rn(dx, dx), __fmul_rn(dy, dy)),
                             __fmul_rn(dz, dz));
        bool valid = (d2 <= R2);
        unsigned long long bal = __ballot(valid);
        if (valid) {
            int pos = base + __popcll(bal & ((1ull << lane) - 1ull));
            if (pos < CAP) nbr[(size_t)q * CAP + pos] = (unsigned short)k;
        }
        base += __popcll(bal);
    }
    if (lane == 0) cnt[q] = (base > CAP) ? CAP : base;
}

// ---------------------------------------------------------------------------
// Sparse attention v2: one wave per query, lane = p*32 + h*4 + s.
// Lane owns dims [8s, 8s+8) of head h; the two 32-lane halves (p) process
// neighbors j and j+1 -> each K/V load instr reads 2 contiguous 512B rows.
// bf16 KV (4 MB) is L2-resident. Score reduced over the 4 s-lanes via
// shfl_xor(1,2); halves merged at the end via shfl_xor(32).
// ---------------------------------------------------------------------------
__global__ __launch_bounds__(256) void sparse_attn2(const float* __restrict__ Q,
                                                    const ushort_t* __restrict__ KV,
                                                    const unsigned short* __restrict__ nbr,
                                                    const int* __restrict__ cnt,
                                                    float* __restrict__ O) {
    const int q    = blockIdx.x * 4 + (threadIdx.x >> 6);
    const int lane = threadIdx.x & 63;
    const int p    = lane >> 5;        // neighbor-pair half
    const int h    = (lane >> 2) & 7;  // head
    const int s    = lane & 3;         // dim segment: dims [8s, 8s+8)

    // q fragment, pre-scaled by 1/sqrt(HD)
    const float* qrow = Q + (size_t)q * FDIM + h * HD + s * 8;
    float qv[8];
    {
        float4 a = *(const float4*)(qrow);
        float4 b = *(const float4*)(qrow + 4);
        qv[0] = a.x; qv[1] = a.y; qv[2] = a.z; qv[3] = a.w;
        qv[4] = b.x; qv[5] = b.y; qv[6] = b.z; qv[7] = b.w;
#pragma unroll
        for (int i = 0; i < 8; ++i) qv[i] *= 0.17677669529663687f;
    }

    float o[8];
#pragma unroll
    for (int i = 0; i < 8; ++i) o[i] = 0.f;
    float m = -3e38f, l = 0.f;

    const int n = cnt[q];
    const unsigned short* nl = nbr + (size_t)q * CAP;
    const int koff = h * HD + s * 8;  // within K half; V half = +256

    for (int j = 0; j < n; j += 2) {
        const int  jj   = j + p;
        const bool live = (jj < n);
        const int  k    = nl[live ? jj : j];
        const ushort_t* row = KV + (size_t)k * 512 + koff;

        u8vec k8 = *(const u8vec*)(row);        // 16B, coalesced per half
        u8vec v8 = *(const u8vec*)(row + 256);  // prefetch V early

        float part = 0.f;
#pragma unroll
        for (int i = 0; i < 8; ++i) part = fmaf(qv[i], bf2f(k8[i]), part);
        part += __shfl_xor(part, 1, 64);
        part += __shfl_xor(part, 2, 64);

        const float sc    = live ? part : -INFINITY;
        const float newm  = fmaxf(m, sc);
        const float scale = __expf(m - newm);   // m finite: always defined
        const float pw    = __expf(sc - newm);  // dead lane: exp(-inf)=0
        l = l * scale + pw;
#pragma unroll
        for (int i = 0; i < 8; ++i)
            o[i] = o[i] * scale + pw * bf2f(v8[i]);
        m = newm;
    }

    // merge the two neighbor halves (xor 32)
    const float gm  = fmaxf(m, __shfl_xor(m, 32, 64));
    const float sc2 = __expf(m - gm);
    l *= sc2;
#pragma unroll
    for (int i = 0; i < 8; ++i) o[i] *= sc2;
    l += __shfl_xor(l, 32, 64);
#pragma unroll
    for (int i = 0; i < 8; ++i) o[i] += __shfl_xor(o[i], 32, 64);

    if (p == 0) {
        const float inv = 1.0f / l;
        float* orow = O + (size_t)q * FDIM + h * HD + s * 8;
        float4 t0, t1;
        t0.x = o[0] * inv; t0.y = o[1] * inv; t0.z = o[2] * inv; t0.w = o[3] * inv;
        t1.x = o[4] * inv; t1.y = o[5] * inv; t1.z = o[6] * inv; t1.w = o[7] * inv;
        *(float4*)(orow)     = t0;
        *(float4*)(orow + 4) = t1;
    }
}

// ---------------------------------------------------------------------------
extern "C" void kernel_launch(void* const* d_in, const int* in_sizes, int n_in,
                              void* d_out, int out_size, void* d_ws, size_t ws_size,
                              hipStream_t stream) {
    const float* cur_feats   = (const float*)d_in[0];
    const float* hist_feats  = (const float*)d_in[1];
    const float* cur_coords  = (const float*)d_in[2];
    const float* hist_coords = (const float*)d_in[3];
    const float* Wq = (const float*)d_in[4];
    const float* bq = (const float*)d_in[5];
    const float* Wk = (const float*)d_in[6];
    const float* bk = (const float*)d_in[7];
    const float* Wv = (const float*)d_in[8];
    const float* bv = (const float*)d_in[9];
    const float* Wo = (const float*)d_in[10];
    const float* bo = (const float*)d_in[11];
    float* out = (float*)d_out;

    char* w = (char*)d_ws;
    const size_t MB4 = (size_t)NQ * FDIM * sizeof(float);  // 4 MiB
    float*          Qb  = (float*)(w);
    ushort_t*       KV  = (ushort_t*)(w + MB4);            // 4096 x 512 bf16 = 4 MiB
    float*          Ob  = (float*)(w + 2 * MB4);
    unsigned short* nbr = (unsigned short*)(w + 3 * MB4);
    int*            cnt = (int*)(w + 3 * MB4 + (size_t)NQ * CAP * sizeof(unsigned short));

    qkv_gemm<<<dim3(4, 64, 3), 256, 0, stream>>>(cur_feats, hist_feats,
                                                 Wq, bq, Wk, bk, Wv, bv, Qb, KV);

    build_nbr<<<NQ / 4, 256, 0, stream>>>(cur_coords, hist_coords, nbr, cnt);

    sparse_attn2<<<NQ / 4, 256, 0, stream>>>(Qb, KV, nbr, cnt, Ob);

    gemm_bt<<<dim3(4, 64), 256, 0, stream>>>(Ob, Wo, bo, out);
}

// Round 3
// 157.123 us; speedup vs baseline: 1.7410x; 1.1288x over previous
//
#include <hip/hip_runtime.h>
#include <math.h>

#define FDIM 256
#define NH 8
#define HD 32
#define NQ 4096
#define NKEY 4096
#define CAP 512
#define R2 9.0f

typedef _Float16 half8 __attribute__((ext_vector_type(8)));
typedef _Float16 half4v __attribute__((ext_vector_type(4)));
typedef float f32x4 __attribute__((ext_vector_type(4)));
typedef unsigned short ushort_t;

// castbuf layout (f16 elements)
#define CB_CUR  0
#define CB_HIST 1048576
#define CB_WQ   2097152
#define CB_WK   2162688
#define CB_WV   2228224
#define CB_WO   2293760
#define CB_F4_TOTAL 589824  // total float4 groups (2359296 floats / 4)

// ---------------------------------------------------------------------------
// Cast all GEMM inputs fp32 -> fp16 into one contiguous buffer.
// ---------------------------------------------------------------------------
__global__ __launch_bounds__(256) void cast_all(const float* __restrict__ cur,
                                                const float* __restrict__ hist,
                                                const float* __restrict__ Wq,
                                                const float* __restrict__ Wk,
                                                const float* __restrict__ Wv,
                                                const float* __restrict__ Wo,
                                                _Float16* __restrict__ dst) {
    const int stride = gridDim.x * blockDim.x;
    for (int i4 = blockIdx.x * blockDim.x + threadIdx.x; i4 < CB_F4_TOTAL; i4 += stride) {
        const float* src;
        int base;
        if (i4 < 262144)      { src = cur;  base = 0; }
        else if (i4 < 524288) { src = hist; base = 262144; }
        else if (i4 < 540672) { src = Wq;   base = 524288; }
        else if (i4 < 557056) { src = Wk;   base = 540672; }
        else if (i4 < 573440) { src = Wv;   base = 557056; }
        else                  { src = Wo;   base = 573440; }
        float4 v = ((const float4*)src)[i4 - base];
        half4v h;
        h[0] = (_Float16)v.x; h[1] = (_Float16)v.y;
        h[2] = (_Float16)v.z; h[3] = (_Float16)v.w;
        ((half4v*)dst)[i4] = h;
    }
}

// ---------------------------------------------------------------------------
// MFMA GEMM core: C[m][n] = sum_k A[m][k] * W[n][k]  (A,W fp16 row-major,
// K = 256). Wave tile 16(M) x 64(N): 1 A-frag + 4 B-frags + 4 MFMA per
// k-step, 8 k-steps. No LDS: fragments are direct 16B loads (A-operand
// lane map A[m=lane&15][k=quad*8+j]; B-operand B[k=quad*8+j][n=lane&15],
// which for X*W^T means 8 contiguous f16 of a W row). C/D: row=quad*4+r,
// col=lane&15 (m89/m91 verified).
// Block = 4 waves stacked in M -> 64x64 tile. Grid (N/64, M/64, z).
// ---------------------------------------------------------------------------
__device__ __forceinline__ void mfma_tile_16x64(const _Float16* __restrict__ A,
                                                const _Float16* __restrict__ W,
                                                int m0, int n0, int wave, int lane,
                                                f32x4 acc[4]) {
    const int row  = lane & 15;
    const int quad = lane >> 4;
    const _Float16* aptr = A + (size_t)(m0 + wave * 16 + row) * 256 + quad * 8;
    const _Float16* wptr = W + (size_t)(n0 + row) * 256 + quad * 8;
#pragma unroll
    for (int i = 0; i < 4; ++i) acc[i] = (f32x4){0.f, 0.f, 0.f, 0.f};
#pragma unroll
    for (int k0 = 0; k0 < 8; ++k0) {
        half8 a = *(const half8*)(aptr + k0 * 32);
#pragma unroll
        for (int nt = 0; nt < 4; ++nt) {
            half8 b = *(const half8*)(wptr + (size_t)nt * 16 * 256 + k0 * 32);
            acc[nt] = __builtin_amdgcn_mfma_f32_16x16x32_f16(a, b, acc[nt], 0, 0, 0);
        }
    }
}

// Fused QKV projection. z=0: Q fp32 out. z=1/2: K/V fp16 into interleaved KV.
__global__ __launch_bounds__(256) void qkv_mfma(const _Float16* __restrict__ cb,
                                                const float* __restrict__ bq,
                                                const float* __restrict__ bk,
                                                const float* __restrict__ bv,
                                                float* __restrict__ Qout,
                                                _Float16* __restrict__ KV) {
    const int z    = blockIdx.z;
    const int wave = threadIdx.x >> 6;
    const int lane = threadIdx.x & 63;
    const int m0   = blockIdx.y * 64;
    const int n0   = blockIdx.x * 64;

    const _Float16* A = (z == 0) ? (cb + CB_CUR) : (cb + CB_HIST);
    const _Float16* W = (z == 0) ? (cb + CB_WQ) : (z == 1) ? (cb + CB_WK) : (cb + CB_WV);
    const float* bias = (z == 0) ? bq : (z == 1) ? bk : bv;

    f32x4 acc[4];
    mfma_tile_16x64(A, W, m0, n0, wave, lane, acc);

    const int col  = lane & 15;
    const int quad = lane >> 4;
    float bs[4];
#pragma unroll
    for (int nt = 0; nt < 4; ++nt) bs[nt] = bias[n0 + nt * 16 + col];

    if (z == 0) {
#pragma unroll
        for (int nt = 0; nt < 4; ++nt)
#pragma unroll
            for (int r = 0; r < 4; ++r)
                Qout[(size_t)(m0 + wave * 16 + quad * 4 + r) * 256 + n0 + nt * 16 + col] =
                    acc[nt][r] + bs[nt];
    } else {
        const int off = (z == 1) ? 0 : 256;
#pragma unroll
        for (int nt = 0; nt < 4; ++nt)
#pragma unroll
            for (int r = 0; r < 4; ++r)
                KV[(size_t)(m0 + wave * 16 + quad * 4 + r) * 512 + off + n0 + nt * 16 + col] =
                    (_Float16)(acc[nt][r] + bs[nt]);
    }
}

// O-projection: out fp32 = Ob_f16 * Wo_f16^T + bo
__global__ __launch_bounds__(256) void o_mfma(const _Float16* __restrict__ Ob,
                                              const _Float16* __restrict__ Wo,
                                              const float* __restrict__ bo,
                                              float* __restrict__ out) {
    const int wave = threadIdx.x >> 6;
    const int lane = threadIdx.x & 63;
    const int m0   = blockIdx.y * 64;
    const int n0   = blockIdx.x * 64;

    f32x4 acc[4];
    mfma_tile_16x64(Ob, Wo, m0, n0, wave, lane, acc);

    const int col  = lane & 15;
    const int quad = lane >> 4;
#pragma unroll
    for (int nt = 0; nt < 4; ++nt) {
        const float b = bo[n0 + nt * 16 + col];
#pragma unroll
        for (int r = 0; r < 4; ++r)
            out[(size_t)(m0 + wave * 16 + quad * 4 + r) * 256 + n0 + nt * 16 + col] =
                acc[nt][r] + b;
    }
}

// ---------------------------------------------------------------------------
// Neighbor list build: exact reference fp32 arithmetic order (no contraction).
// ---------------------------------------------------------------------------
__global__ __launch_bounds__(256) void build_nbr(const float* __restrict__ qc,
                                                 const float* __restrict__ kc,
                                                 ushort_t* __restrict__ nbr,
                                                 int* __restrict__ cnt) {
    const int q    = blockIdx.x * 4 + (threadIdx.x >> 6);
    const int lane = threadIdx.x & 63;
    const float qx = qc[q * 3 + 0];
    const float qy = qc[q * 3 + 1];
    const float qz = qc[q * 3 + 2];
    int base = 0;
    for (int k0 = 0; k0 < NKEY; k0 += 64) {
        const int k = k0 + lane;
        float dx = __fsub_rn(qx, kc[k * 3 + 0]);
        float dy = __fsub_rn(qy, kc[k * 3 + 1]);
        float dz = __fsub_rn(qz, kc[k * 3 + 2]);
        float d2 = __fadd_rn(__fadd_rn(__fmul_rn(dx, dx), __fmul_rn(dy, dy)),
                             __fmul_rn(dz, dz));
        bool valid = (d2 <= R2);
        unsigned long long bal = __ballot(valid);
        if (valid) {
            int pos = base + __popcll(bal & ((1ull << lane) - 1ull));
            if (pos < CAP) nbr[(size_t)q * CAP + pos] = (ushort_t)k;
        }
        base += __popcll(bal);
    }
    if (lane == 0) cnt[q] = (base > CAP) ? CAP : base;
}

// ---------------------------------------------------------------------------
// Sparse attention v3: wave per query, lane = p*32 + h*4 + s.
// Two independent online-softmax states per lane (neighbors j+p and j+2+p)
// -> 2x ILP on the serial rescale chain, 2x memory-level parallelism.
// fp16 KV (L2-resident). Output Ob in fp16 (feeds o_mfma directly).
// ---------------------------------------------------------------------------
__global__ __launch_bounds__(256) void sparse_attn3(const float* __restrict__ Q,
                                                    const _Float16* __restrict__ KV,
                                                    const ushort_t* __restrict__ nbr,
                                                    const int* __restrict__ cnt,
                                                    _Float16* __restrict__ Ob) {
    const int q    = blockIdx.x * 4 + (threadIdx.x >> 6);
    const int lane = threadIdx.x & 63;
    const int p    = lane >> 5;
    const int h    = (lane >> 2) & 7;
    const int s    = lane & 3;

    const float* qrow = Q + (size_t)q * FDIM + h * HD + s * 8;
    float qv[8];
    {
        float4 a = *(const float4*)(qrow);
        float4 b = *(const float4*)(qrow + 4);
        qv[0] = a.x; qv[1] = a.y; qv[2] = a.z; qv[3] = a.w;
        qv[4] = b.x; qv[5] = b.y; qv[6] = b.z; qv[7] = b.w;
#pragma unroll
        for (int i = 0; i < 8; ++i) qv[i] *= 0.17677669529663687f;
    }

    float oA[8], oB[8];
#pragma unroll
    for (int i = 0; i < 8; ++i) { oA[i] = 0.f; oB[i] = 0.f; }
    float mA = -3e38f, lA = 0.f;
    float mB = -3e38f, lB = 0.f;

    const int n = cnt[q];
    const ushort_t* nl = nbr + (size_t)q * CAP;
    const int koff = h * HD + s * 8;

    for (int j = 0; j < n; j += 4) {
        const int  jA = j + p;
        const int  jB = j + 2 + p;
        const bool liveA = (jA < n);
        const bool liveB = (jB < n);
        const int  kA = nl[liveA ? jA : 0];
        const int  kB = nl[liveB ? jB : 0];
        const _Float16* rowA = KV + (size_t)kA * 512 + koff;
        const _Float16* rowB = KV + (size_t)kB * 512 + koff;
        half8 k8A = *(const half8*)(rowA);
        half8 v8A = *(const half8*)(rowA + 256);
        half8 k8B = *(const half8*)(rowB);
        half8 v8B = *(const half8*)(rowB + 256);

        float pa = 0.f, pb = 0.f;
#pragma unroll
        for (int i = 0; i < 8; ++i) {
            pa = fmaf(qv[i], (float)k8A[i], pa);
            pb = fmaf(qv[i], (float)k8B[i], pb);
        }
        pa += __shfl_xor(pa, 1, 64); pa += __shfl_xor(pa, 2, 64);
        pb += __shfl_xor(pb, 1, 64); pb += __shfl_xor(pb, 2, 64);

        const float scA = liveA ? pa : -INFINITY;
        const float scB = liveB ? pb : -INFINITY;

        const float nmA = fmaxf(mA, scA);
        const float sfA = __expf(mA - nmA);
        const float pwA = __expf(scA - nmA);
        lA = lA * sfA + pwA;
#pragma unroll
        for (int i = 0; i < 8; ++i)
            oA[i] = oA[i] * sfA + pwA * (float)v8A[i];
        mA = nmA;

        const float nmB = fmaxf(mB, scB);
        const float sfB = __expf(mB - nmB);
        const float pwB = __expf(scB - nmB);
        lB = lB * sfB + pwB;
#pragma unroll
        for (int i = 0; i < 8; ++i)
            oB[i] = oB[i] * sfB + pwB * (float)v8B[i];
        mB = nmB;
    }

    // merge state B into A (per lane)
    float m = fmaxf(mA, mB);
    const float sA = __expf(mA - m), sB = __expf(mB - m);
    float l = lA * sA + lB * sB;
    float o[8];
#pragma unroll
    for (int i = 0; i < 8; ++i) o[i] = oA[i] * sA + oB[i] * sB;

    // merge the two 32-lane halves
    const float gm  = fmaxf(m, __shfl_xor(m, 32, 64));
    const float sc2 = __expf(m - gm);
    l *= sc2;
#pragma unroll
    for (int i = 0; i < 8; ++i) o[i] *= sc2;
    l += __shfl_xor(l, 32, 64);
#pragma unroll
    for (int i = 0; i < 8; ++i) o[i] += __shfl_xor(o[i], 32, 64);

    if (p == 0) {
        const float inv = 1.0f / l;
        half8 ho;
#pragma unroll
        for (int i = 0; i < 8; ++i) ho[i] = (_Float16)(o[i] * inv);
        *(half8*)(Ob + (size_t)q * FDIM + h * HD + s * 8) = ho;
    }
}

// ---------------------------------------------------------------------------
extern "C" void kernel_launch(void* const* d_in, const int* in_sizes, int n_in,
                              void* d_out, int out_size, void* d_ws, size_t ws_size,
                              hipStream_t stream) {
    const float* cur_feats   = (const float*)d_in[0];
    const float* hist_feats  = (const float*)d_in[1];
    const float* cur_coords  = (const float*)d_in[2];
    const float* hist_coords = (const float*)d_in[3];
    const float* bq = (const float*)d_in[5];
    const float* bk = (const float*)d_in[7];
    const float* bv = (const float*)d_in[9];
    const float* bo = (const float*)d_in[11];
    float* out = (float*)d_out;

    char* w = (char*)d_ws;
    float*     Qb   = (float*)(w);                         // 4 MiB fp32
    _Float16*  KV   = (_Float16*)(w + (4 << 20));          // 4096x512 f16 = 4 MiB
    ushort_t*  nbr  = (ushort_t*)(w + (8 << 20));          // 4 MiB
    int*       cnt  = (int*)(w + (12 << 20));              // 16 KiB
    _Float16*  Ob   = (_Float16*)(w + (12 << 20) + (64 << 10));  // 2 MiB
    _Float16*  cb   = (_Float16*)(w + (15 << 20));         // cast buffer ~4.5 MiB

    cast_all<<<1024, 256, 0, stream>>>(cur_feats, hist_feats,
                                       (const float*)d_in[4], (const float*)d_in[6],
                                       (const float*)d_in[8], (const float*)d_in[10], cb);

    build_nbr<<<NQ / 4, 256, 0, stream>>>(cur_coords, hist_coords, nbr, cnt);

    qkv_mfma<<<dim3(4, 64, 3), 256, 0, stream>>>(cb, bq, bk, bv, Qb, KV);

    sparse_attn3<<<NQ / 4, 256, 0, stream>>>(Qb, KV, nbr, cnt, Ob);

    o_mfma<<<dim3(4, 64), 256, 0, stream>>>(Ob, cb + CB_WO, bo, out);
}